// Round 1
// baseline (322.416 us; speedup 1.0000x reference)
//
#include <hip/hip_runtime.h>

// TTM: y = x @ W where W[1024,4096] is the merged TT-matrix of (g1,g2,g3).
// ws layout: [0,4MiB) G12 fp32 | [4,12MiB) Wt bf16 [4096][1024] | [12,28MiB) Xb bf16 [8192][1024]

#define B_ROWS 8192
#define K_DIM  1024
#define N_DIM  4096

typedef __bf16 bf16x8 __attribute__((ext_vector_type(8)));
typedef float  f32x4  __attribute__((ext_vector_type(4)));

__device__ __forceinline__ unsigned int f2bf(float f) {
    unsigned int x = __float_as_uint(f);
    return (x + 0x7FFFu + ((x >> 16) & 1u)) >> 16;   // RNE bf16
}

// G12[i,p,j,q,s] = sum_r g1[i,p,r] * g2[r,j,q,s]   (1,048,576 elems)
__global__ __launch_bounds__(256) void merge12(const float* __restrict__ g1,
                                               const float* __restrict__ g2,
                                               float* __restrict__ G12) {
    int o = blockIdx.x * 256 + threadIdx.x;
    int s = o & 63;
    int q = (o >> 6) & 15;
    int j = (o >> 10) & 7;
    int p = (o >> 13) & 15;
    int i = o >> 17;
    const float* g1p = g1 + (i * 16 + p) * 64;
    const float* g2p = g2 + (j * 16 + q) * 64 + s;
    float acc = 0.f;
#pragma unroll 8
    for (int r = 0; r < 64; ++r)
        acc += g1p[r] * g2p[r * 8192];
    G12[o] = acc;
}

// Wt[n][kin] (bf16, n=(p*16+q)*16+m, kin=(i*8+j)*16+k) = sum_s G12[i,p,j,q,s]*g3[s,k,m]
__global__ __launch_bounds__(256) void merge3(const float* __restrict__ G12,
                                              const float* __restrict__ g3,
                                              ushort* __restrict__ Wt) {
    int o = blockIdx.x * 256 + threadIdx.x;   // 262,144 threads
    int kin = o & 1023;
    int pq  = o >> 10;
    int i = kin >> 7, j = (kin >> 4) & 7, k = kin & 15;
    int p = pq >> 4,  q = pq & 15;
    const float* gsrc = G12 + ((((i * 16 + p) * 8 + j) * 16 + q) * 64);
    float acc[16] = {};
    for (int s = 0; s < 64; ++s) {
        float a = gsrc[s];
        const float4* g3v = (const float4*)(g3 + (s * 16 + k) * 16);
#pragma unroll
        for (int mq = 0; mq < 4; ++mq) {
            float4 v = g3v[mq];
            acc[mq * 4 + 0] += a * v.x;
            acc[mq * 4 + 1] += a * v.y;
            acc[mq * 4 + 2] += a * v.z;
            acc[mq * 4 + 3] += a * v.w;
        }
    }
#pragma unroll
    for (int m = 0; m < 16; ++m)
        Wt[(size_t)(pq * 16 + m) * K_DIM + kin] = (ushort)f2bf(acc[m]);
}

// x fp32 -> bf16, 8 elems/thread
__global__ __launch_bounds__(256) void castx(const float* __restrict__ x,
                                             ushort* __restrict__ Xb) {
    size_t o = (size_t)blockIdx.x * 256 + threadIdx.x;  // 1,048,576 threads
    const float4* xp = (const float4*)(x + o * 8);
    float4 v0 = xp[0], v1 = xp[1];
    uint4 out;
    out.x = f2bf(v0.x) | (f2bf(v0.y) << 16);
    out.y = f2bf(v0.z) | (f2bf(v0.w) << 16);
    out.z = f2bf(v1.x) | (f2bf(v1.y) << 16);
    out.w = f2bf(v1.z) | (f2bf(v1.w) << 16);
    *(uint4*)(Xb + o * 8) = out;
}

// C[8192,4096] = Xb[8192,1024] * Wt[4096,1024]^T   (bf16 in, fp32 out)
// m97 structure: 128x128 tile, 4 waves (2x2), BK=32, global_load_lds width=16.
__global__ __launch_bounds__(256) void gemm_bf16(const ushort* __restrict__ Xb,
                                                 const ushort* __restrict__ Wt,
                                                 float* __restrict__ C) {
    __shared__ ushort ldsA[128 * 32];
    __shared__ ushort ldsB[128 * 32];

    const int t = threadIdx.x;
    const int w = t >> 6;
    const int l = t & 63;

    const int bm = blockIdx.x >> 5;   // 64 row-tiles
    const int bn = blockIdx.x & 31;   // 32 col-tiles
    const int rowBase = bm * 128;
    const int colBase = bn * 128;

    const int wr = w >> 1, wc = w & 1;
    const int fr = l & 15;
    const int kh = l >> 4;

    f32x4 acc[4][4] = {};

    // staging: thread t loads 16B from row (t>>2), col-bytes (t&3)*16 of the half-tile
    const int srow = t >> 2;
    const int scol = (t & 3) * 8;
    const ushort* gA = Xb + (size_t)(rowBase + srow) * K_DIM + scol;
    const ushort* gB = Wt + (size_t)(colBase + srow) * K_DIM + scol;
    ushort* lA0 = &ldsA[w * 512];   // wave-uniform LDS base (HW adds lane*16B)
    ushort* lB0 = &ldsB[w * 512];

    for (int kt = 0; kt < K_DIM / 32; ++kt) {
        const int k0 = kt * 32;
        __builtin_amdgcn_global_load_lds(
            (const __attribute__((address_space(1))) void*)(gA + k0),
            (__attribute__((address_space(3))) void*)(lA0), 16, 0, 0);
        __builtin_amdgcn_global_load_lds(
            (const __attribute__((address_space(1))) void*)(gA + (size_t)64 * K_DIM + k0),
            (__attribute__((address_space(3))) void*)(lA0 + 2048), 16, 0, 0);
        __builtin_amdgcn_global_load_lds(
            (const __attribute__((address_space(1))) void*)(gB + k0),
            (__attribute__((address_space(3))) void*)(lB0), 16, 0, 0);
        __builtin_amdgcn_global_load_lds(
            (const __attribute__((address_space(1))) void*)(gB + (size_t)64 * K_DIM + k0),
            (__attribute__((address_space(3))) void*)(lB0 + 2048), 16, 0, 0);
        __syncthreads();   // compiler emits s_waitcnt vmcnt(0) before s_barrier

        bf16x8 af[4], bf[4];
#pragma unroll
        for (int m = 0; m < 4; ++m)
            af[m] = *(const bf16x8*)&ldsA[(wr * 64 + m * 16 + fr) * 32 + kh * 8];
#pragma unroll
        for (int n = 0; n < 4; ++n)
            bf[n] = *(const bf16x8*)&ldsB[(wc * 64 + n * 16 + fr) * 32 + kh * 8];

#pragma unroll
        for (int m = 0; m < 4; ++m)
#pragma unroll
            for (int n = 0; n < 4; ++n)
                acc[m][n] = __builtin_amdgcn_mfma_f32_16x16x32_bf16(af[m], bf[n], acc[m][n], 0, 0, 0);
        __syncthreads();
    }

    // epilogue: C/D layout col = lane&15, row = (lane>>4)*4 + reg  [verified m89/m91]
    const int cr = (l >> 4) * 4;
#pragma unroll
    for (int m = 0; m < 4; ++m) {
        const int row0 = rowBase + wr * 64 + m * 16 + cr;
#pragma unroll
        for (int n = 0; n < 4; ++n) {
            const int col = colBase + wc * 64 + n * 16 + fr;
#pragma unroll
            for (int r = 0; r < 4; ++r)
                C[(size_t)(row0 + r) * N_DIM + col] = acc[m][n][r];
        }
    }
}

extern "C" void kernel_launch(void* const* d_in, const int* in_sizes, int n_in,
                              void* d_out, int out_size, void* d_ws, size_t ws_size,
                              hipStream_t stream) {
    const float* x  = (const float*)d_in[0];   // [8192,1024]
    const float* g1 = (const float*)d_in[1];   // [1,8,16,64]
    const float* g2 = (const float*)d_in[2];   // [64,8,16,64]
    const float* g3 = (const float*)d_in[3];   // [64,16,16,1]
    float* out = (float*)d_out;                // [8192,4096]

    char* ws = (char*)d_ws;                    // need >= 28 MiB
    float*  G12 = (float*)ws;                          // 4 MiB
    ushort* Wt  = (ushort*)(ws + (4u << 20));          // 8 MiB
    ushort* Xb  = (ushort*)(ws + (12u << 20));         // 16 MiB

    merge12<<<4096, 256, 0, stream>>>(g1, g2, G12);
    merge3 <<<1024, 256, 0, stream>>>(G12, g3, Wt);
    castx  <<<4096, 256, 0, stream>>>(x, Xb);
    gemm_bf16<<<dim3(64 * 32), 256, 0, stream>>>(Xb, Wt, out);
}

// Round 2
// 254.786 us; speedup vs baseline: 1.2654x; 1.2654x over previous
//
#include <hip/hip_runtime.h>

// TTM: y = x @ W, W[1024,4096] = merged TT cores (g1,g2,g3), bf16 GEMM w/ fp32 acc.
// ws layout: [0,8MiB) Wt bf16 [4096][1024] | [8,24MiB) Xb bf16 [8192][1024]

#define K_DIM  1024
#define N_DIM  4096

typedef __bf16 bf16x8 __attribute__((ext_vector_type(8)));
typedef float  f32x4  __attribute__((ext_vector_type(4)));

__device__ __forceinline__ unsigned int f2bf(float f) {
    unsigned int x = __float_as_uint(f);
    return (x + 0x7FFFu + ((x >> 16) & 1u)) >> 16;   // RNE bf16
}

__device__ __forceinline__ void barx() {
    asm volatile("" ::: "memory");
    __builtin_amdgcn_s_barrier();
    asm volatile("" ::: "memory");
}

__device__ __forceinline__ void stage16(const ushort* src, const ushort* dst) {
    __builtin_amdgcn_global_load_lds(
        (const __attribute__((address_space(1))) void*)src,
        (__attribute__((address_space(3))) void*)dst, 16, 0, 0);
}

// ---------------- W merge: one block per (p,q); Wt[n=(p,q,m)][k=(i,j,k3)] ----------------
__global__ __launch_bounds__(256) void mergeW(const float* __restrict__ g1,
                                              const float* __restrict__ g2,
                                              const float* __restrict__ g3,
                                              ushort* __restrict__ Wt) {
    __shared__ float g1s[512];     // [i][r] 8x64
    __shared__ float S[4096];      // [j][s][i] -> ((j*64+s)*8+i)
    __shared__ float g3s[16384];   // swizzled: float4 (s,k,m4) at sk*4 + (m4 ^ ((k>>1)&3))
    const int t = threadIdx.x;
    const int p = blockIdx.x >> 4, q = blockIdx.x & 15;

    for (int u = t; u < 512; u += 256) {
        int i = u >> 6, r = u & 63;
        g1s[u] = g1[(i * 16 + p) * 64 + r];
    }
    for (int u = t; u < 4096; u += 256) {          // u = (s*16+k)*4 + m4
        int m4 = u & 3, sk = u >> 2, k = sk & 15;
        float4 v = ((const float4*)g3)[u];
        ((float4*)g3s)[sk * 4 + (m4 ^ ((k >> 1) & 3))] = v;
    }
    __syncthreads();

    // phase 1: S[j][s][i] = sum_r g1[i,p,r]*g2[r,j,q,s]
    for (int u = t; u < 512; u += 256) {
        int jj = u >> 6, ss = u & 63;
        float acc[8] = {};
        const float* g2p = g2 + (jj * 16 + q) * 64 + ss;
#pragma unroll 8
        for (int r = 0; r < 64; ++r) {
            float v = g2p[r * 8192];
#pragma unroll
            for (int i = 0; i < 8; ++i) acc[i] += g1s[i * 64 + r] * v;
        }
        float4* Sp = (float4*)&S[u * 8];
        Sp[0] = make_float4(acc[0], acc[1], acc[2], acc[3]);
        Sp[1] = make_float4(acc[4], acc[5], acc[6], acc[7]);
    }
    __syncthreads();

    // phase 2: Wt[(pq*16+m)][kin] = sum_s S[j][s][i]*g3[s,k,m]
    const int pq = p * 16 + q;
#pragma unroll
    for (int c = 0; c < 4; ++c) {
        int kin = c * 256 + t;
        int i = kin >> 7, j = (kin >> 4) & 7, k = kin & 15;
        float acc[16] = {};
        for (int s = 0; s < 64; ++s) {
            float a = S[(j * 64 + s) * 8 + i];
            const float4* g3v = (const float4*)&g3s[(s * 16 + k) * 16];
#pragma unroll
            for (int m4 = 0; m4 < 4; ++m4) {
                float4 v = g3v[m4 ^ ((k >> 1) & 3)];
                acc[m4 * 4 + 0] += a * v.x;
                acc[m4 * 4 + 1] += a * v.y;
                acc[m4 * 4 + 2] += a * v.z;
                acc[m4 * 4 + 3] += a * v.w;
            }
        }
#pragma unroll
        for (int m = 0; m < 16; ++m)
            Wt[(size_t)(pq * 16 + m) * K_DIM + kin] = (ushort)f2bf(acc[m]);
    }
}

// ---------------- x fp32 -> bf16 ----------------
__global__ __launch_bounds__(256) void castx(const float* __restrict__ x,
                                             ushort* __restrict__ Xb) {
    size_t o = (size_t)blockIdx.x * 256 + threadIdx.x;
    const float4* xp = (const float4*)(x + o * 8);
    float4 v0 = xp[0], v1 = xp[1];
    uint4 out;
    out.x = f2bf(v0.x) | (f2bf(v0.y) << 16);
    out.y = f2bf(v0.z) | (f2bf(v0.w) << 16);
    out.z = f2bf(v1.x) | (f2bf(v1.y) << 16);
    out.w = f2bf(v1.z) | (f2bf(v1.w) << 16);
    *(uint4*)(Xb + o * 8) = out;
}

// ---------------- GEMM: 256x256 tile, 8 waves, BK=32, 4-slot ring, counted vmcnt ----------------
#define MF(mm, nn, aa, bb) acc[mm][nn] = __builtin_amdgcn_mfma_f32_16x16x32_bf16(aa, bb, acc[mm][nn], 0, 0, 0)

__global__ __launch_bounds__(512, 2) void gemm_bf16(const ushort* __restrict__ Xb,
                                                    const ushort* __restrict__ Wt,
                                                    float* __restrict__ C) {
    __shared__ ushort lds[65536];   // 4 slots x (A 8192 + B 8192) ushorts = 128 KiB

    const int t = threadIdx.x;
    const int w = t >> 6, l = t & 63;
    const int wr = w >> 2, wc = w & 3;          // 2M x 4N waves, each 128x64 output
    const int fr = l & 15, cc = l >> 4;

    const int bid = blockIdx.x;                 // 512 blocks, 512%8==0 -> simple XCD swizzle
    const int swz = (bid & 7) * 64 + (bid >> 3);
    const int tileM = (swz >> 4) * 256;
    const int tileN = (swz & 15) * 256;

    // ds_read byte offsets within a slot (XOR-swizzled chunks: g = c ^ ((row>>1)&3))
    int offA[8], offB[4];
#pragma unroll
    for (int m = 0; m < 8; ++m) {
        int R = wr * 128 + m * 16 + fr;
        offA[m] = (R * 32 + ((cc ^ ((R >> 1) & 3)) * 8)) * 2;
    }
#pragma unroll
    for (int n = 0; n < 4; ++n) {
        int R = wc * 64 + n * 16 + fr;
        offB[n] = (8192 + R * 32 + ((cc ^ ((R >> 1) & 3)) * 8)) * 2;
    }

    // staging: linear LDS dest (wave-uniform base + lane*16B), pre-swizzled global source
    const ushort* srcA[2]; const ushort* srcB[2];
    int dstAoff[2], dstBoff[2];
#pragma unroll
    for (int j = 0; j < 2; ++j) {
        int s = j * 512 + t;                    // 16B slot id in [0,1024)
        int r = s >> 2, pch = s & 3;
        int cs = pch ^ ((r >> 1) & 3);          // source chunk (inverse == same involution)
        srcA[j] = Xb + (size_t)(tileM + r) * K_DIM + cs * 8;
        srcB[j] = Wt + (size_t)(tileN + r) * K_DIM + cs * 8;
        dstAoff[j] = j * 4096 + w * 512;
        dstBoff[j] = 8192 + j * 4096 + w * 512;
    }

    f32x4 acc[8][4] = {};

    // prologue: stage K-tiles 0,1,2 into slots 0,1,2 (12 loads/thread)
#pragma unroll
    for (int pt = 0; pt < 3; ++pt) {
        ushort* sl = lds + pt * 16384;
        const int ko = pt * 32;
        stage16(srcA[0] + ko, sl + dstAoff[0]);
        stage16(srcA[1] + ko, sl + dstAoff[1]);
        stage16(srcB[0] + ko, sl + dstBoff[0]);
        stage16(srcB[1] + ko, sl + dstBoff[1]);
    }
    asm volatile("s_waitcnt vmcnt(8)" ::: "memory");   // tile 0 landed
    barx();

#pragma unroll 4
    for (int kt = 0; kt < 32; ++kt) {
        const char* slb = (const char*)(lds + (kt & 3) * 16384);
        ushort* ssl = lds + ((kt + 3) & 3) * 16384;
        int kst = kt + 3; if (kst > 31) kst = 0;       // uniform load count; clamp src
        const int ko = kst * 32;

        // ---- phase 1: frags A0-3 + B0-3, stage next A, 16 MFMA ----
        bf16x8 a0 = *(const bf16x8*)(slb + offA[0]);
        bf16x8 a1 = *(const bf16x8*)(slb + offA[1]);
        bf16x8 a2 = *(const bf16x8*)(slb + offA[2]);
        bf16x8 a3 = *(const bf16x8*)(slb + offA[3]);
        bf16x8 b0 = *(const bf16x8*)(slb + offB[0]);
        bf16x8 b1 = *(const bf16x8*)(slb + offB[1]);
        bf16x8 b2 = *(const bf16x8*)(slb + offB[2]);
        bf16x8 b3 = *(const bf16x8*)(slb + offB[3]);
        stage16(srcA[0] + ko, ssl + dstAoff[0]);
        stage16(srcA[1] + ko, ssl + dstAoff[1]);
        barx();
        __builtin_amdgcn_s_setprio(1);
        MF(0,0,a0,b0); MF(0,1,a0,b1); MF(0,2,a0,b2); MF(0,3,a0,b3);
        MF(1,0,a1,b0); MF(1,1,a1,b1); MF(1,2,a1,b2); MF(1,3,a1,b3);
        MF(2,0,a2,b0); MF(2,1,a2,b1); MF(2,2,a2,b2); MF(2,3,a2,b3);
        MF(3,0,a3,b0); MF(3,1,a3,b1); MF(3,2,a3,b2); MF(3,3,a3,b3);
        __builtin_amdgcn_s_setprio(0);
        barx();

        // ---- phase 2: frags A4-7 (B reused in regs), stage next B, 16 MFMA ----
        bf16x8 a4 = *(const bf16x8*)(slb + offA[4]);
        bf16x8 a5 = *(const bf16x8*)(slb + offA[5]);
        bf16x8 a6 = *(const bf16x8*)(slb + offA[6]);
        bf16x8 a7 = *(const bf16x8*)(slb + offA[7]);
        stage16(srcB[0] + ko, ssl + dstBoff[0]);
        stage16(srcB[1] + ko, ssl + dstBoff[1]);
        asm volatile("s_waitcnt vmcnt(8)" ::: "memory");  // tile kt+1 landed; kt+2/kt+3 stay in flight
        barx();
        __builtin_amdgcn_s_setprio(1);
        MF(4,0,a4,b0); MF(4,1,a4,b1); MF(4,2,a4,b2); MF(4,3,a4,b3);
        MF(5,0,a5,b0); MF(5,1,a5,b1); MF(5,2,a5,b2); MF(5,3,a5,b3);
        MF(6,0,a6,b0); MF(6,1,a6,b1); MF(6,2,a6,b2); MF(6,3,a6,b3);
        MF(7,0,a7,b0); MF(7,1,a7,b1); MF(7,2,a7,b2); MF(7,3,a7,b3);
        __builtin_amdgcn_s_setprio(0);
        barx();
    }
    asm volatile("s_waitcnt vmcnt(0)" ::: "memory");   // drain garbage prefetches before endpgm

    // epilogue: C/D layout col = lane&15, row = (lane>>4)*4 + reg
    const int cr = (l >> 4) * 4;
#pragma unroll
    for (int m = 0; m < 8; ++m) {
        const int row0 = tileM + wr * 128 + m * 16 + cr;
#pragma unroll
        for (int n = 0; n < 4; ++n) {
            const int col = tileN + wc * 64 + n * 16 + fr;
            float* Cp = C + (size_t)row0 * N_DIM + col;
#pragma unroll
            for (int r = 0; r < 4; ++r)
                Cp[(size_t)r * N_DIM] = acc[m][n][r];
        }
    }
}

extern "C" void kernel_launch(void* const* d_in, const int* in_sizes, int n_in,
                              void* d_out, int out_size, void* d_ws, size_t ws_size,
                              hipStream_t stream) {
    const float* x  = (const float*)d_in[0];   // [8192,1024]
    const float* g1 = (const float*)d_in[1];   // [1,8,16,64]
    const float* g2 = (const float*)d_in[2];   // [64,8,16,64]
    const float* g3 = (const float*)d_in[3];   // [64,16,16,1]
    float* out = (float*)d_out;                // [8192,4096]

    char* ws = (char*)d_ws;
    ushort* Wt = (ushort*)ws;                  // 8 MiB
    ushort* Xb = (ushort*)(ws + (8u << 20));   // 16 MiB

    mergeW<<<256, 256, 0, stream>>>(g1, g2, g3, Wt);
    castx <<<4096, 256, 0, stream>>>(x, Xb);
    gemm_bf16<<<512, 512, 0, stream>>>(Xb, Wt, out);
}

// Round 3
// 254.090 us; speedup vs baseline: 1.2689x; 1.0027x over previous
//
#include <hip/hip_runtime.h>

// TTM: y = x @ W, W[1024,4096] = merged TT cores (g1,g2,g3), bf16 GEMM w/ fp32 acc.
// ws layout: [0,8MiB) Wt bf16 [4096][1024] | [8,24MiB) Xb bf16 [8192][1024]

#define K_DIM  1024
#define N_DIM  4096

typedef __bf16 bf16x8 __attribute__((ext_vector_type(8)));
typedef float  f32x4  __attribute__((ext_vector_type(4)));

__device__ __forceinline__ unsigned int f2bf(float f) {
    unsigned int x = __float_as_uint(f);
    return (x + 0x7FFFu + ((x >> 16) & 1u)) >> 16;   // RNE bf16
}

__device__ __forceinline__ void barx() {
    asm volatile("" ::: "memory");
    __builtin_amdgcn_s_barrier();
    asm volatile("" ::: "memory");
}

__device__ __forceinline__ void stage16(const ushort* src, const ushort* dst) {
    __builtin_amdgcn_global_load_lds(
        (const __attribute__((address_space(1))) void*)src,
        (__attribute__((address_space(3))) void*)dst, 16, 0, 0);
}

// ---------------- W merge: one block per (p,q); Wt[n=(p,q,m)][k=(i,j,k3)] ----------------
__global__ __launch_bounds__(256) void mergeW(const float* __restrict__ g1,
                                              const float* __restrict__ g2,
                                              const float* __restrict__ g3,
                                              ushort* __restrict__ Wt) {
    __shared__ float g1s[512];     // [i][r] 8x64
    __shared__ float S[4096];      // [j][s][i] -> ((j*64+s)*8+i)
    __shared__ float g3s[16384];   // swizzled: float4 (s,k,m4) at sk*4 + (m4 ^ ((k>>1)&3))
    const int t = threadIdx.x;
    const int p = blockIdx.x >> 4, q = blockIdx.x & 15;

    for (int u = t; u < 512; u += 256) {
        int i = u >> 6, r = u & 63;
        g1s[u] = g1[(i * 16 + p) * 64 + r];
    }
    for (int u = t; u < 4096; u += 256) {          // u = (s*16+k)*4 + m4
        int m4 = u & 3, sk = u >> 2, k = sk & 15;
        float4 v = ((const float4*)g3)[u];
        ((float4*)g3s)[sk * 4 + (m4 ^ ((k >> 1) & 3))] = v;
    }
    __syncthreads();

    // phase 1: S[j][s][i] = sum_r g1[i,p,r]*g2[r,j,q,s]
    for (int u = t; u < 512; u += 256) {
        int jj = u >> 6, ss = u & 63;
        float acc[8] = {};
        const float* g2p = g2 + (jj * 16 + q) * 64 + ss;
#pragma unroll 8
        for (int r = 0; r < 64; ++r) {
            float v = g2p[r * 8192];
#pragma unroll
            for (int i = 0; i < 8; ++i) acc[i] += g1s[i * 64 + r] * v;
        }
        float4* Sp = (float4*)&S[u * 8];
        Sp[0] = make_float4(acc[0], acc[1], acc[2], acc[3]);
        Sp[1] = make_float4(acc[4], acc[5], acc[6], acc[7]);
    }
    __syncthreads();

    // phase 2: Wt[(pq*16+m)][kin] = sum_s S[j][s][i]*g3[s,k,m]
    const int pq = p * 16 + q;
#pragma unroll
    for (int c = 0; c < 4; ++c) {
        int kin = c * 256 + t;
        int i = kin >> 7, j = (kin >> 4) & 7, k = kin & 15;
        float acc[16] = {};
        for (int s = 0; s < 64; ++s) {
            float a = S[(j * 64 + s) * 8 + i];
            const float4* g3v = (const float4*)&g3s[(s * 16 + k) * 16];
#pragma unroll
            for (int m4 = 0; m4 < 4; ++m4) {
                float4 v = g3v[m4 ^ ((k >> 1) & 3)];
                acc[m4 * 4 + 0] += a * v.x;
                acc[m4 * 4 + 1] += a * v.y;
                acc[m4 * 4 + 2] += a * v.z;
                acc[m4 * 4 + 3] += a * v.w;
            }
        }
#pragma unroll
        for (int m = 0; m < 16; ++m)
            Wt[(size_t)(pq * 16 + m) * K_DIM + kin] = (ushort)f2bf(acc[m]);
    }
}

// ---------------- x fp32 -> bf16 ----------------
__global__ __launch_bounds__(256) void castx(const float* __restrict__ x,
                                             ushort* __restrict__ Xb) {
    size_t o = (size_t)blockIdx.x * 256 + threadIdx.x;
    const float4* xp = (const float4*)(x + o * 8);
    float4 v0 = xp[0], v1 = xp[1];
    uint4 out;
    out.x = f2bf(v0.x) | (f2bf(v0.y) << 16);
    out.y = f2bf(v0.z) | (f2bf(v0.w) << 16);
    out.z = f2bf(v1.x) | (f2bf(v1.y) << 16);
    out.w = f2bf(v1.z) | (f2bf(v1.w) << 16);
    *(uint4*)(Xb + o * 8) = out;
}

// ---------------- GEMM: 256x256 tile, 8 waves, BK=32, 4-slot ring ----------------
// One barrier + one counted vmcnt(8) per K-tile; stages issue first, then 12 ds_reads,
// then 32 MFMA under setprio(1). Compiler lgkmcnt + wave skew overlap LDS and MFMA pipes.
#define MF(mm, nn, aa, bb) acc[mm][nn] = __builtin_amdgcn_mfma_f32_16x16x32_bf16(aa, bb, acc[mm][nn], 0, 0, 0)

__global__ __launch_bounds__(512, 2) void gemm_bf16(const ushort* __restrict__ Xb,
                                                    const ushort* __restrict__ Wt,
                                                    float* __restrict__ C) {
    __shared__ ushort lds[65536];   // 4 slots x (A 8192 + B 8192) ushorts = 128 KiB

    const int t = threadIdx.x;
    const int w = t >> 6, l = t & 63;
    const int wr = w >> 2, wc = w & 3;          // 2M x 4N waves, each 128x64 output
    const int fr = l & 15, cc = l >> 4;

    const int bid = blockIdx.x;                 // 512 blocks, 512%8==0 -> simple XCD swizzle
    const int swz = (bid & 7) * 64 + (bid >> 3);
    const int tileM = (swz >> 4) * 256;
    const int tileN = (swz & 15) * 256;

    // ds_read byte offsets within a slot (XOR-swizzled chunks: g = c ^ ((row>>1)&3))
    int offA[8], offB[4];
#pragma unroll
    for (int m = 0; m < 8; ++m) {
        int R = wr * 128 + m * 16 + fr;
        offA[m] = (R * 32 + ((cc ^ ((R >> 1) & 3)) * 8)) * 2;
    }
#pragma unroll
    for (int n = 0; n < 4; ++n) {
        int R = wc * 64 + n * 16 + fr;
        offB[n] = (8192 + R * 32 + ((cc ^ ((R >> 1) & 3)) * 8)) * 2;
    }

    // staging: linear LDS dest (wave-uniform base + lane*16B), pre-swizzled global source
    const ushort* srcA[2]; const ushort* srcB[2];
    int dstAoff[2], dstBoff[2];
#pragma unroll
    for (int j = 0; j < 2; ++j) {
        int s = j * 512 + t;                    // 16B slot id in [0,1024)
        int r = s >> 2, pch = s & 3;
        int cs = pch ^ ((r >> 1) & 3);          // source chunk (involution)
        srcA[j] = Xb + (size_t)(tileM + r) * K_DIM + cs * 8;
        srcB[j] = Wt + (size_t)(tileN + r) * K_DIM + cs * 8;
        dstAoff[j] = j * 4096 + w * 512;
        dstBoff[j] = 8192 + j * 4096 + w * 512;
    }

    f32x4 acc[8][4] = {};

    // prologue: stage K-tiles 0,1,2 into slots 0,1,2 (12 loads/thread)
#pragma unroll
    for (int pt = 0; pt < 3; ++pt) {
        ushort* sl = lds + pt * 16384;
        const int ko = pt * 32;
        stage16(srcA[0] + ko, sl + dstAoff[0]);
        stage16(srcA[1] + ko, sl + dstAoff[1]);
        stage16(srcB[0] + ko, sl + dstBoff[0]);
        stage16(srcB[1] + ko, sl + dstBoff[1]);
    }
    asm volatile("s_waitcnt vmcnt(8)" ::: "memory");   // tile 0 landed
    barx();

#pragma unroll 4
    for (int kt = 0; kt < 32; ++kt) {
        const char* slb = (const char*)(lds + (kt & 3) * 16384);
        ushort* ssl = lds + ((kt + 3) & 3) * 16384;   // == slot (kt-1)&3: reads retired pre-barrier
        int kst = kt + 3; if (kst > 31) kst = 0;       // uniform load count; clamp src
        const int ko = kst * 32;

        // issue next-tile stages first (longest latency)
        stage16(srcA[0] + ko, ssl + dstAoff[0]);
        stage16(srcA[1] + ko, ssl + dstAoff[1]);
        stage16(srcB[0] + ko, ssl + dstBoff[0]);
        stage16(srcB[1] + ko, ssl + dstBoff[1]);

        // 12 fragment reads from current slot
        bf16x8 a0 = *(const bf16x8*)(slb + offA[0]);
        bf16x8 a1 = *(const bf16x8*)(slb + offA[1]);
        bf16x8 a2 = *(const bf16x8*)(slb + offA[2]);
        bf16x8 a3 = *(const bf16x8*)(slb + offA[3]);
        bf16x8 b0 = *(const bf16x8*)(slb + offB[0]);
        bf16x8 b1 = *(const bf16x8*)(slb + offB[1]);
        bf16x8 b2 = *(const bf16x8*)(slb + offB[2]);
        bf16x8 b3 = *(const bf16x8*)(slb + offB[3]);
        bf16x8 a4 = *(const bf16x8*)(slb + offA[4]);
        bf16x8 a5 = *(const bf16x8*)(slb + offA[5]);
        bf16x8 a6 = *(const bf16x8*)(slb + offA[6]);
        bf16x8 a7 = *(const bf16x8*)(slb + offA[7]);

        __builtin_amdgcn_s_setprio(1);
        MF(0,0,a0,b0); MF(0,1,a0,b1); MF(0,2,a0,b2); MF(0,3,a0,b3);
        MF(1,0,a1,b0); MF(1,1,a1,b1); MF(1,2,a1,b2); MF(1,3,a1,b3);
        MF(2,0,a2,b0); MF(2,1,a2,b1); MF(2,2,a2,b2); MF(2,3,a2,b3);
        MF(3,0,a3,b0); MF(3,1,a3,b1); MF(3,2,a3,b2); MF(3,3,a3,b3);
        MF(4,0,a4,b0); MF(4,1,a4,b1); MF(4,2,a4,b2); MF(4,3,a4,b3);
        MF(5,0,a5,b0); MF(5,1,a5,b1); MF(5,2,a5,b2); MF(5,3,a5,b3);
        MF(6,0,a6,b0); MF(6,1,a6,b1); MF(6,2,a6,b2); MF(6,3,a6,b3);
        MF(7,0,a7,b0); MF(7,1,a7,b1); MF(7,2,a7,b2); MF(7,3,a7,b3);
        __builtin_amdgcn_s_setprio(0);

        asm volatile("s_waitcnt vmcnt(8)" ::: "memory");  // tile kt+1 landed; kt+2/kt+3 in flight
        barx();
    }
    asm volatile("s_waitcnt vmcnt(0)" ::: "memory");   // drain garbage prefetches before epilogue

    // epilogue: C/D layout col = lane&15, row = (lane>>4)*4 + reg
    const int cr = (l >> 4) * 4;
#pragma unroll
    for (int m = 0; m < 8; ++m) {
        const int row0 = tileM + wr * 128 + m * 16 + cr;
#pragma unroll
        for (int n = 0; n < 4; ++n) {
            const int col = tileN + wc * 64 + n * 16 + fr;
            float* Cp = C + (size_t)row0 * N_DIM + col;
#pragma unroll
            for (int r = 0; r < 4; ++r)
                Cp[(size_t)r * N_DIM] = acc[m][n][r];
        }
    }
}

extern "C" void kernel_launch(void* const* d_in, const int* in_sizes, int n_in,
                              void* d_out, int out_size, void* d_ws, size_t ws_size,
                              hipStream_t stream) {
    const float* x  = (const float*)d_in[0];   // [8192,1024]
    const float* g1 = (const float*)d_in[1];   // [1,8,16,64]
    const float* g2 = (const float*)d_in[2];   // [64,8,16,64]
    const float* g3 = (const float*)d_in[3];   // [64,16,16,1]
    float* out = (float*)d_out;                // [8192,4096]

    char* ws = (char*)d_ws;
    ushort* Wt = (ushort*)ws;                  // 8 MiB
    ushort* Xb = (ushort*)(ws + (8u << 20));   // 16 MiB

    mergeW<<<256, 256, 0, stream>>>(g1, g2, g3, Wt);
    castx <<<4096, 256, 0, stream>>>(x, Xb);
    gemm_bf16<<<512, 512, 0, stream>>>(Xb, Wt, out);
}